// Round 1
// baseline (1865.989 us; speedup 1.0000x reference)
//
#include <hip/hip_runtime.h>
#include <hip/hip_bf16.h>
#include <stdint.h>

#define LB 6
#define BB 32
#define SS 512
#define DD 512
#define HH 8
#define FF_ 2048
#define MM (BB*SS)   // 16384

typedef unsigned short u16;
typedef __attribute__((ext_vector_type(8))) short bf16x8;
typedef __attribute__((ext_vector_type(4))) float f32x4;

#define MFMA16(a,b,c) __builtin_amdgcn_mfma_f32_16x16x32_bf16((a),(b),(c),0,0,0)
#define GLD16(g, l) __builtin_amdgcn_global_load_lds( \
    (const __attribute__((address_space(1))) unsigned int*)(g), \
    (__attribute__((address_space(3))) unsigned int*)(l), 16, 0, 0)

__device__ __forceinline__ u16 f2b(float f){
  unsigned int u = __float_as_uint(f);
  u = u + 0x7FFFu + ((u >> 16) & 1u);
  return (u16)(u >> 16);
}

__device__ __forceinline__ float gelu_f(float x){
  float u = 0.7978845608028654f * (x + 0.044715f * x * x * x);
  return 0.5f * x * (1.0f + tanhf(u));
}

// ---------------- prep: h(fp32)=x, hbf=bf16(x) ----------------
__global__ __launch_bounds__(256) void k_prep(const float* __restrict__ x,
                                              float* __restrict__ h,
                                              u16* __restrict__ hb){
  int i = blockIdx.x * 256 + threadIdx.x;
  float4 v = ((const float4*)x)[i];
  ((float4*)h)[i] = v;
  uint2 p;
  p.x = (unsigned)f2b(v.x) | ((unsigned)f2b(v.y) << 16);
  p.y = (unsigned)f2b(v.z) | ((unsigned)f2b(v.w) << 16);
  ((uint2*)hb)[i] = p;
}

// ---------------- weight transpose + bf16 cast: out[n][k] = in[k][n] ----------------
__global__ __launch_bounds__(256) void k_wt(const float* __restrict__ in,
                                            u16* __restrict__ out, int K, int N){
  size_t ms = (size_t)K * N;
  in  += ms * blockIdx.z;
  out += ms * blockIdx.z;
  int n0 = blockIdx.x * 64, k0 = blockIdx.y * 64;
  __shared__ float tile[64][65];
  int t = threadIdx.x;
  int c = t & 63, rb = t >> 6;
  #pragma unroll
  for (int p = 0; p < 16; p++){
    int k = p * 4 + rb;
    tile[k][c] = in[(size_t)(k0 + k) * N + (n0 + c)];
  }
  __syncthreads();
  #pragma unroll
  for (int p = 0; p < 16; p++){
    int n = p * 4 + rb;
    out[(size_t)(n0 + n) * K + (k0 + c)] = f2b(tile[c][n]);
  }
}

// ---------------- GEMM: out[m][n] = sum_k A[m][k]*Bt[n][k], 128x128 tile ----------------
// EPI: 0 = bf16 store, 1 = fp32 store, 2 = bias+gelu -> bf16, 3 = bias -> fp32
template<int EPI, bool PERM>
__device__ __forceinline__ void gemm_body(const u16* __restrict__ A, const u16* __restrict__ Bt,
    const float* __restrict__ bias, float* __restrict__ outF, u16* __restrict__ outH,
    int N, int K)
{
  __shared__ u16 sA[128*32];
  __shared__ u16 sB[128*32];
  const int t = threadIdx.x;
  const int w = t >> 6, lane = t & 63, lr = lane & 15, lh = lane >> 4;
  const int bm = blockIdx.x * 128, bn = blockIdx.y * 128;
  const int wr = (w >> 1) * 64, wc = (w & 1) * 64;

  f32x4 acc[4][4];
  #pragma unroll
  for (int i = 0; i < 4; i++)
    #pragma unroll
    for (int j = 0; j < 4; j++) acc[i][j] = (f32x4){0.f,0.f,0.f,0.f};

  const int srow = t >> 2;            // 0..63
  const int scol = (t & 3) * 8;       // k element offset
  int b0 = bn + srow, b1 = bn + srow + 64;
  if (PERM){  // head-interleave fold: effective col n <- source col (n&63)*8 + (n>>6)
    b0 = ((b0 & 63) << 3) | (b0 >> 6);
    b1 = ((b1 & 63) << 3) | (b1 >> 6);
  }
  const u16* gA0 = A  + (size_t)(bm + srow) * K + scol;
  const u16* gA1 = gA0 + (size_t)64 * K;
  const u16* gB0 = Bt + (size_t)b0 * K + scol;
  const u16* gB1 = Bt + (size_t)b1 * K + scol;
  u16* lA = sA + w * 512;
  u16* lB = sB + w * 512;

  for (int k0 = 0; k0 < K; k0 += 32){
    GLD16(gA0 + k0, lA);
    GLD16(gA1 + k0, lA + 2048);
    GLD16(gB0 + k0, lB);
    GLD16(gB1 + k0, lB + 2048);
    __syncthreads();
    bf16x8 af[4], bfr[4];
    #pragma unroll
    for (int i = 0; i < 4; i++) af[i]  = *(const bf16x8*)&sA[(wr + i*16 + lr)*32 + lh*8];
    #pragma unroll
    for (int j = 0; j < 4; j++) bfr[j] = *(const bf16x8*)&sB[(wc + j*16 + lr)*32 + lh*8];
    #pragma unroll
    for (int i = 0; i < 4; i++)
      #pragma unroll
      for (int j = 0; j < 4; j++)
        acc[i][j] = MFMA16(af[i], bfr[j], acc[i][j]);
    __syncthreads();
  }

  #pragma unroll
  for (int i = 0; i < 4; i++){
    int row = bm + wr + i*16 + lh*4;
    #pragma unroll
    for (int j = 0; j < 4; j++){
      int col = bn + wc + j*16 + lr;
      float bv = (EPI >= 2) ? bias[col] : 0.f;
      #pragma unroll
      for (int r = 0; r < 4; r++){
        float v = acc[i][j][r];
        size_t o = (size_t)(row + r) * N + col;
        if (EPI == 0) outH[o] = f2b(v);
        else if (EPI == 1) outF[o] = v;
        else if (EPI == 2) outH[o] = f2b(gelu_f(v + bv));
        else outF[o] = v + bv;
      }
    }
  }
}

template<int EPI>
__global__ __launch_bounds__(256) void k_gemm(const u16* A, const u16* Bt, const float* bias,
                                              float* outF, u16* outH, int N, int K){
  gemm_body<EPI,false>(A, Bt, bias, outF, outH, N, K);
}

__global__ __launch_bounds__(256) void k_qkv(const u16* A, const u16* Bq, const u16* Bk, const u16* Bv,
                                             u16* oq, u16* ok, u16* ov){
  const u16* Bt = (blockIdx.z == 0) ? Bq : (blockIdx.z == 1) ? Bk : Bv;
  u16* out = (blockIdx.z == 0) ? oq : (blockIdx.z == 1) ? ok : ov;
  gemm_body<0,true>(A, Bt, nullptr, nullptr, out, DD, DD);
}

// ---------------- flash attention: block = (qtile 64, head, batch), 4 waves ----------------
__global__ __launch_bounds__(256) void k_attn(const u16* __restrict__ Q, const u16* __restrict__ Kp,
                                              const u16* __restrict__ V, u16* __restrict__ O){
  const int qt = blockIdx.x, hh = blockIdx.y, b = blockIdx.z;
  __shared__ u16 Qs[64*64];
  __shared__ u16 Ks[64*64];
  __shared__ u16 Vt[64*64];   // transposed [dk][kv], double-key swizzled
  __shared__ u16 Ps[64*64];   // P tile, per-wave rows, swizzled
  const int t = threadIdx.x, w = t >> 6, lane = t & 63, lr = lane & 15, lh = lane >> 4;
  const size_t base = ((size_t)b * SS) * DD + (size_t)hh * 64;

  const int srow = t >> 3;                               // 0..31 (+32 for 2nd pass)
  const int gcol = (((t & 7) ^ (srow & 7)) << 3);        // pre-swizzled source column
  {
    const u16* g = Q + base + (size_t)(qt*64 + srow) * DD + gcol;
    GLD16(g,                   Qs + w*512);
    GLD16(g + (size_t)32*DD,   Qs + 2048 + w*512);
  }

  float mreg[4], lreg[4];
  f32x4 ofr[4];
  #pragma unroll
  for (int r = 0; r < 4; r++){ mreg[r] = -1e30f; lreg[r] = 0.f; }
  #pragma unroll
  for (int j = 0; j < 4; j++) ofr[j] = (f32x4){0.f,0.f,0.f,0.f};

  const int qswz = (lr & 7) << 3;

  for (int kt = 0; kt < 8; kt++){
    {
      const u16* g = Kp + base + (size_t)(kt*64 + srow) * DD + gcol;
      GLD16(g,                 Ks + w*512);
      GLD16(g + (size_t)32*DD, Ks + 2048 + w*512);
    }
    {
      const int dk0 = (t & 7) * 8, kv = (t >> 3) * 2;
      const u16* g = V + base + (size_t)(kt*64 + kv) * DD + dk0;
      uint4 r0 = *(const uint4*)g;
      uint4 r1 = *(const uint4*)(g + DD);
      const u16* e0 = (const u16*)&r0;
      const u16* e1 = (const u16*)&r1;
      #pragma unroll
      for (int i = 0; i < 8; i++){
        int dk = dk0 + i;
        int sw = ((((dk >> 3) ^ dk) & 7) << 3);
        *(unsigned int*)&Vt[dk*64 + (kv ^ sw)] =
            (unsigned int)e0[i] | ((unsigned int)e1[i] << 16);
      }
    }
    __syncthreads();

    // QK^T (16 rows per wave x 64 kv cols)
    bf16x8 a0 = *(const bf16x8*)&Qs[(w*16+lr)*64 + ((lh*8) ^ qswz)];
    bf16x8 a1 = *(const bf16x8*)&Qs[(w*16+lr)*64 + ((32 + lh*8) ^ qswz)];
    f32x4 sc[4];
    #pragma unroll
    for (int j = 0; j < 4; j++){
      bf16x8 b0 = *(const bf16x8*)&Ks[(j*16+lr)*64 + ((lh*8) ^ qswz)];
      bf16x8 b1 = *(const bf16x8*)&Ks[(j*16+lr)*64 + ((32 + lh*8) ^ qswz)];
      f32x4 z = (f32x4){0.f,0.f,0.f,0.f};
      z = MFMA16(a0, b0, z);
      z = MFMA16(a1, b1, z);
      sc[j] = z;
    }

    // online softmax (rows = lh*4+r, reduce across 16 lanes)
    float pr[4][4];
    float esc[4];
    #pragma unroll
    for (int r = 0; r < 4; r++){
      float mx = fmaxf(fmaxf(sc[0][r], sc[1][r]), fmaxf(sc[2][r], sc[3][r]));
      mx = fmaxf(mx, __shfl_xor(mx, 1));
      mx = fmaxf(mx, __shfl_xor(mx, 2));
      mx = fmaxf(mx, __shfl_xor(mx, 4));
      mx = fmaxf(mx, __shfl_xor(mx, 8));
      mx *= 0.125f;   // scale by 1/sqrt(64) (monotone, safe to scale max)
      float m2 = fmaxf(mreg[r], mx);
      float scl = __expf(mreg[r] - m2);
      mreg[r] = m2;
      float s = 0.f;
      #pragma unroll
      for (int j = 0; j < 4; j++){
        float p = __expf(sc[j][r]*0.125f - m2);
        pr[j][r] = p;
        s += p;
      }
      s += __shfl_xor(s, 1);
      s += __shfl_xor(s, 2);
      s += __shfl_xor(s, 4);
      s += __shfl_xor(s, 8);
      lreg[r] = lreg[r]*scl + s;
      esc[r] = scl;
    }

    // write P (bf16, swizzled); each wave owns its 16 rows -> no barrier needed
    #pragma unroll
    for (int j = 0; j < 4; j++)
      #pragma unroll
      for (int r = 0; r < 4; r++){
        int prow = w*16 + lh*4 + r;
        int pcol = j*16 + lr;
        Ps[prow*64 + (pcol ^ (((lh*4 + r) & 7) << 3))] = f2b(pr[j][r]);
      }

    // rescale O
    #pragma unroll
    for (int j = 0; j < 4; j++)
      #pragma unroll
      for (int r = 0; r < 4; r++) ofr[j][r] *= esc[r];

    // PV
    bf16x8 pa0 = *(const bf16x8*)&Ps[(w*16+lr)*64 + ((lh*8) ^ qswz)];
    bf16x8 pa1 = *(const bf16x8*)&Ps[(w*16+lr)*64 + ((32 + lh*8) ^ qswz)];
    #pragma unroll
    for (int j = 0; j < 4; j++){
      int dkr = j*16 + lr;
      int sw = ((((dkr >> 3) ^ dkr) & 7) << 3);
      bf16x8 v0 = *(const bf16x8*)&Vt[dkr*64 + ((lh*8) ^ sw)];
      bf16x8 v1 = *(const bf16x8*)&Vt[dkr*64 + ((32 + lh*8) ^ sw)];
      ofr[j] = MFMA16(pa0, v0, ofr[j]);
      ofr[j] = MFMA16(pa1, v1, ofr[j]);
    }
    __syncthreads();
  }

  #pragma unroll
  for (int j = 0; j < 4; j++)
    #pragma unroll
    for (int r = 0; r < 4; r++){
      float v = ofr[j][r] / lreg[r];
      O[base + (size_t)(qt*64 + w*16 + lh*4 + r) * DD + j*16 + lr] = f2b(v);
    }
}

// ---------------- fused residual add + LayerNorm: h = LN(hin + add) ----------------
__global__ __launch_bounds__(256) void k_ln(const float* __restrict__ hin, const float* __restrict__ add,
    const float* __restrict__ g, const float* __restrict__ be,
    float* __restrict__ hout, u16* __restrict__ hb){
  const int row = blockIdx.x;
  const int t = threadIdx.x;
  const size_t baseo = (size_t)row * DD;
  float v0 = hin[baseo + t]       + add[baseo + t];
  float v1 = hin[baseo + t + 256] + add[baseo + t + 256];
  float s = v0 + v1, q = v0*v0 + v1*v1;
  #pragma unroll
  for (int m = 32; m >= 1; m >>= 1){ s += __shfl_xor(s, m); q += __shfl_xor(q, m); }
  __shared__ float sh[8];
  const int w = t >> 6;
  if ((t & 63) == 0){ sh[w] = s; sh[4 + w] = q; }
  __syncthreads();
  s = sh[0] + sh[1] + sh[2] + sh[3];
  q = sh[4] + sh[5] + sh[6] + sh[7];
  float mean = s * (1.f/512.f);
  float var  = q * (1.f/512.f) - mean*mean;
  float rstd = rsqrtf(var + 1e-5f);
  float o0 = g[t]     * ((v0 - mean) * rstd) + be[t];
  float o1 = g[t+256] * ((v1 - mean) * rstd) + be[t+256];
  hout[baseo + t]       = o0;
  hout[baseo + t + 256] = o1;
  hb[baseo + t]       = f2b(o0);
  hb[baseo + t + 256] = f2b(o1);
}

// ---------------- launch ----------------
extern "C" void kernel_launch(void* const* d_in, const int* in_sizes, int n_in,
                              void* d_out, int out_size, void* d_ws, size_t ws_size,
                              hipStream_t stream){
  const float* x   = (const float*)d_in[0];
  const float* WQ  = (const float*)d_in[1];
  const float* WK  = (const float*)d_in[2];
  const float* WV  = (const float*)d_in[3];
  const float* WO  = (const float*)d_in[4];
  const float* K1  = (const float*)d_in[5];
  const float* B1  = (const float*)d_in[6];
  const float* K2  = (const float*)d_in[7];
  const float* B2  = (const float*)d_in[8];
  const float* G1  = (const float*)d_in[9];
  const float* BE1 = (const float*)d_in[10];
  const float* G2  = (const float*)d_in[11];
  const float* BE2 = (const float*)d_in[12];
  float* hF = (float*)d_out;

  char* wp = (char*)d_ws;
  size_t off = 0;
  auto a16 = [&](size_t elems)->u16*{ u16* p = (u16*)(wp + off); off += elems*sizeof(u16); return p; };
  u16* WQt = a16((size_t)LB*DD*DD);
  u16* WKt = a16((size_t)LB*DD*DD);
  u16* WVt = a16((size_t)LB*DD*DD);
  u16* WOt = a16((size_t)LB*DD*DD);
  u16* K1t = a16((size_t)LB*DD*FF_);
  u16* K2t = a16((size_t)LB*DD*FF_);
  u16* hbf = a16((size_t)MM*DD);
  u16* qbf = a16((size_t)MM*DD);
  u16* kbf = a16((size_t)MM*DD);
  u16* vbf = a16((size_t)MM*DD);
  u16* abf = a16((size_t)MM*DD);
  u16* ff1 = qbf;  // alias: qbf..abf region = MM x FF_ bf16, q/k/v/a dead when ff1 is live
  float* tmpF = (float*)(wp + off); off += (size_t)MM*DD*sizeof(float);
  (void)ws_size; (void)in_sizes; (void)n_in; (void)out_size;

  k_prep<<<MM*DD/4/256, 256, 0, stream>>>(x, hF, hbf);
  k_wt<<<dim3(8,8,LB),        256, 0, stream>>>(WQ, WQt, DD, DD);
  k_wt<<<dim3(8,8,LB),        256, 0, stream>>>(WK, WKt, DD, DD);
  k_wt<<<dim3(8,8,LB),        256, 0, stream>>>(WV, WVt, DD, DD);
  k_wt<<<dim3(8,8,LB),        256, 0, stream>>>(WO, WOt, DD, DD);
  k_wt<<<dim3(FF_/64,8,LB),   256, 0, stream>>>(K1, K1t, DD, FF_);
  k_wt<<<dim3(8,FF_/64,LB),   256, 0, stream>>>(K2, K2t, FF_, DD);

  for (int l = 0; l < LB; l++){
    const u16* wq = WQt + (size_t)l*DD*DD;
    const u16* wk = WKt + (size_t)l*DD*DD;
    const u16* wv = WVt + (size_t)l*DD*DD;
    const u16* wo = WOt + (size_t)l*DD*DD;
    const u16* k1 = K1t + (size_t)l*DD*FF_;
    const u16* k2 = K2t + (size_t)l*DD*FF_;

    k_qkv<<<dim3(MM/128, DD/128, 3), 256, 0, stream>>>(hbf, wq, wk, wv, qbf, kbf, vbf);
    k_attn<<<dim3(SS/64, HH, BB), 256, 0, stream>>>(qbf, kbf, vbf, abf);
    k_gemm<1><<<dim3(MM/128, DD/128), 256, 0, stream>>>(abf, wo, nullptr, tmpF, nullptr, DD, DD);
    k_ln<<<MM, 256, 0, stream>>>(hF, tmpF, G1 + l*DD, BE1 + l*DD, hF, hbf);
    k_gemm<2><<<dim3(MM/128, FF_/128), 256, 0, stream>>>(hbf, k1, B1 + (size_t)l*FF_, nullptr, ff1, FF_, DD);
    k_gemm<3><<<dim3(MM/128, DD/128), 256, 0, stream>>>(ff1, k2, B2 + l*DD, tmpF, nullptr, DD, FF_);
    k_ln<<<MM, 256, 0, stream>>>(hF, tmpF, G2 + l*DD, BE2 + l*DD, hF, hbf);
  }
}